// Round 1
// baseline (1171.168 us; speedup 1.0000x reference)
//
#include <hip/hip_runtime.h>

typedef unsigned short u16;
typedef unsigned int u32;
typedef __bf16 bf16x8 __attribute__((ext_vector_type(8)));
typedef u16 u16x8 __attribute__((ext_vector_type(8)));
typedef float f32x4 __attribute__((ext_vector_type(4)));

#define NH 24
#define SL 2048
#define DM 3072
#define HD 128
#define NB 2
#define MM (NB*SL)   // 4096
#define NE (3*DM)    // 9216

__device__ __forceinline__ float b2f(u16 u) { return __builtin_bit_cast(float, (u32)u << 16); }
__device__ __forceinline__ u16 f2b(float f) {
  u32 x = __builtin_bit_cast(u32, f);
  return (u16)((x + 0x7fffu + ((x >> 16) & 1u)) >> 16);   // RNE
}
__device__ __forceinline__ float fexp2(float x) {
#if __has_builtin(__builtin_amdgcn_exp2f)
  return __builtin_amdgcn_exp2f(x);
#else
  return exp2f(x);
#endif
}

__device__ __forceinline__ void stage16(const u16* g, u16* l, int lane) {
#if __has_builtin(__builtin_amdgcn_global_load_lds)
  // LDS dest is wave-uniform base; lane i's 16B land at l + i*16B.
  __builtin_amdgcn_global_load_lds((const __attribute__((address_space(1))) void*)g,
                                   (__attribute__((address_space(3))) void*)l, 16, 0, 0);
#else
  reinterpret_cast<u16x8*>(l)[lane] = *reinterpret_cast<const u16x8*>(g);
#endif
}

// ---------------- fp32 -> bf16 bulk convert ----------------
__global__ __launch_bounds__(256) void cvt_kernel(const float* __restrict__ src,
                                                  u16* __restrict__ dst, int n4) {
  int i = blockIdx.x * 256 + threadIdx.x;
  if (i >= n4) return;
  float4 v = reinterpret_cast<const float4*>(src)[i];
  u32 lo = (u32)f2b(v.x) | ((u32)f2b(v.y) << 16);
  u32 hi = (u32)f2b(v.z) | ((u32)f2b(v.w) << 16);
  reinterpret_cast<uint2*>(dst)[i] = make_uint2(lo, hi);
}

// ---------------- QKV GEMM: C = A * B^T -> scatter to q/k/v (B,H,L,Hd) bf16 ----------------
// A: [4096][3072] bf16, Bw: [9216][3072] bf16. 128x128 tile, BK=32, 4 waves (2x2 of 64x64).
__global__ __launch_bounds__(256) void gemm_qkv(const u16* __restrict__ A, const u16* __restrict__ Bw,
                                                u16* __restrict__ qb, u16* __restrict__ kb,
                                                u16* __restrict__ vb) {
  __shared__ __align__(16) u16 Asm[128*32];
  __shared__ __align__(16) u16 Bsm[128*32];
  const int tid = threadIdx.x;
  const int w = tid >> 6, lane = tid & 63;
  const int fq = lane >> 4, fr = lane & 15;
  const int wr = w >> 1, wc = w & 1;
  const int m0 = blockIdx.x * 128;
  const int e0 = blockIdx.y * 128;
  const int K = DM;
  const int c0 = 2*w, c1 = 2*w + 1;
  const int row0 = lane >> 2;           // 0..15 within 16-row chunk
  const int koff = (lane & 3) * 8;      // bf16 elems within 32-wide k

  f32x4 acc[4][4] = {};

  for (int kt = 0; kt < K; kt += 32) {
    __syncthreads();
    stage16(A + (size_t)(m0 + c0*16 + row0)*K + kt + koff, Asm + c0*512, lane);
    stage16(A + (size_t)(m0 + c1*16 + row0)*K + kt + koff, Asm + c1*512, lane);
    stage16(Bw + (size_t)(e0 + c0*16 + row0)*K + kt + koff, Bsm + c0*512, lane);
    stage16(Bw + (size_t)(e0 + c1*16 + row0)*K + kt + koff, Bsm + c1*512, lane);
    __syncthreads();   // compiler drains vmcnt before s_barrier
    bf16x8 af[4], bfr[4];
#pragma unroll
    for (int m = 0; m < 4; ++m)
      af[m] = *reinterpret_cast<const bf16x8*>(Asm + (wr*64 + m*16 + fr)*32 + fq*8);
#pragma unroll
    for (int n = 0; n < 4; ++n)
      bfr[n] = *reinterpret_cast<const bf16x8*>(Bsm + (wc*64 + n*16 + fr)*32 + fq*8);
#pragma unroll
    for (int m = 0; m < 4; ++m)
#pragma unroll
      for (int n = 0; n < 4; ++n)
        acc[m][n] = __builtin_amdgcn_mfma_f32_16x16x32_bf16(af[m], bfr[n], acc[m][n], 0, 0, 0);
  }

  // epilogue: tile cols e0..e0+127 are exactly one (s,h) head (e0 % 128 == 0)
  const int s = e0 / DM;
  const int h = (e0 % DM) >> 7;
  const int b = m0 >> 11;
  const int l0 = m0 & (SL - 1);
  u16* outb = (s == 0) ? qb : (s == 1) ? kb : vb;
  outb += ((size_t)(b*NH + h)*SL + l0) * HD;
#pragma unroll
  for (int m = 0; m < 4; ++m)
#pragma unroll
    for (int n = 0; n < 4; ++n)
#pragma unroll
      for (int j = 0; j < 4; ++j) {
        int rr = wr*64 + m*16 + fq*4 + j;
        int cc = wc*64 + n*16 + fr;
        outb[(size_t)rr*HD + cc] = f2b(acc[m][n][j]);
      }
}

// ---------------- proj GEMM: Y(fp32) = A * B^T ----------------
__global__ __launch_bounds__(256) void gemm_proj(const u16* __restrict__ A, const u16* __restrict__ Bw,
                                                 float* __restrict__ Y) {
  __shared__ __align__(16) u16 Asm[128*32];
  __shared__ __align__(16) u16 Bsm[128*32];
  const int tid = threadIdx.x;
  const int w = tid >> 6, lane = tid & 63;
  const int fq = lane >> 4, fr = lane & 15;
  const int wr = w >> 1, wc = w & 1;
  const int m0 = blockIdx.x * 128;
  const int e0 = blockIdx.y * 128;
  const int K = DM;
  const int c0 = 2*w, c1 = 2*w + 1;
  const int row0 = lane >> 2;
  const int koff = (lane & 3) * 8;

  f32x4 acc[4][4] = {};

  for (int kt = 0; kt < K; kt += 32) {
    __syncthreads();
    stage16(A + (size_t)(m0 + c0*16 + row0)*K + kt + koff, Asm + c0*512, lane);
    stage16(A + (size_t)(m0 + c1*16 + row0)*K + kt + koff, Asm + c1*512, lane);
    stage16(Bw + (size_t)(e0 + c0*16 + row0)*K + kt + koff, Bsm + c0*512, lane);
    stage16(Bw + (size_t)(e0 + c1*16 + row0)*K + kt + koff, Bsm + c1*512, lane);
    __syncthreads();
    bf16x8 af[4], bfr[4];
#pragma unroll
    for (int m = 0; m < 4; ++m)
      af[m] = *reinterpret_cast<const bf16x8*>(Asm + (wr*64 + m*16 + fr)*32 + fq*8);
#pragma unroll
    for (int n = 0; n < 4; ++n)
      bfr[n] = *reinterpret_cast<const bf16x8*>(Bsm + (wc*64 + n*16 + fr)*32 + fq*8);
#pragma unroll
    for (int m = 0; m < 4; ++m)
#pragma unroll
      for (int n = 0; n < 4; ++n)
        acc[m][n] = __builtin_amdgcn_mfma_f32_16x16x32_bf16(af[m], bfr[n], acc[m][n], 0, 0, 0);
  }

  float* y = Y + (size_t)m0*DM + e0;
#pragma unroll
  for (int m = 0; m < 4; ++m)
#pragma unroll
    for (int n = 0; n < 4; ++n)
#pragma unroll
      for (int j = 0; j < 4; ++j) {
        int rr = wr*64 + m*16 + fq*4 + j;
        int cc = wc*64 + n*16 + fr;
        y[(size_t)rr*DM + cc] = acc[m][n][j];
      }
}

// ---------------- RMSNorm over Hd=128, in place, one wave per row ----------------
__global__ __launch_bounds__(256) void rmsnorm_k(u16* __restrict__ buf, const float* __restrict__ scale,
                                                 float extra) {
  int row = blockIdx.x * 4 + (threadIdx.x >> 6);
  int lane = threadIdx.x & 63;
  u16* p = buf + (size_t)row * HD + lane * 2;
  u32 u = *reinterpret_cast<const u32*>(p);
  float a = b2f((u16)(u & 0xffffu));
  float c = b2f((u16)(u >> 16));
  float ss = a*a + c*c;
#pragma unroll
  for (int m = 32; m; m >>= 1) ss += __shfl_xor(ss, m, 64);
  float rr = rsqrtf(ss * (1.0f/128.0f) + 1e-6f);
  float s0 = scale[lane*2] * extra;
  float s1 = scale[lane*2 + 1] * extra;
  u32 o = (u32)f2b(a*rr*s0) | ((u32)f2b(c*rr*s1) << 16);
  *reinterpret_cast<u32*>(p) = o;
}

// ---------------- flash attention fwd, non-causal ----------------
// grid (L/64, B*H), 4 waves; wave w owns q rows [q0+w*16, +16). KV tile = 64.
// q is pre-scaled by q_scale * log2(e)/sqrt(128); k by k_scale. exp via exp2.
__global__ __launch_bounds__(256) void attn_kernel(const u16* __restrict__ qb, const u16* __restrict__ kb,
                                                   const u16* __restrict__ vb, u16* __restrict__ ob) {
  __shared__ __align__(16) u16 Ksm[64*136];   // [key][hd], padded stride 136 (2-way banks)
  __shared__ __align__(16) u16 Vsm[128*72];   // transposed [hd][key], stride 72
  __shared__ __align__(16) u16 Psm[64*72];    // [qrow][key], stride 72
  const int tid = threadIdx.x;
  const int w = tid >> 6, lane = tid & 63;
  const int fq = lane >> 4, fr = lane & 15;
  const int bh = blockIdx.y;
  const int q0 = blockIdx.x * 64;
  const u16* qrow = qb + (size_t)bh * SL * HD;
  const u16* krow = kb + (size_t)bh * SL * HD;
  const u16* vrow = vb + (size_t)bh * SL * HD;

  // Q fragments in registers: rows q0 + w*16 + fr, 4 k-chunks of 32
  bf16x8 qf[4];
#pragma unroll
  for (int kk = 0; kk < 4; ++kk)
    qf[kk] = *reinterpret_cast<const bf16x8*>(qrow + (size_t)(q0 + w*16 + fr)*HD + kk*32 + fq*8);

  f32x4 o[8] = {};           // 8 hd-tiles of 16
  float mrow[4], lrow[4];
#pragma unroll
  for (int j = 0; j < 4; ++j) { mrow[j] = -1e30f; lrow[j] = 0.0f; }

  for (int kt = 0; kt < SL; kt += 64) {
    __syncthreads();         // prev iter's PV reads done before restage
    // stage K (row-major, padded) and V (transposed)
    for (int c = tid; c < 1024; c += 256) {
      int key = c >> 4;
      int cc = (c & 15) * 8;
      *reinterpret_cast<bf16x8*>(Ksm + key*136 + cc) =
          *reinterpret_cast<const bf16x8*>(krow + (size_t)(kt + key)*HD + cc);
      u16x8 vv = *reinterpret_cast<const u16x8*>(vrow + (size_t)(kt + key)*HD + cc);
#pragma unroll
      for (int j2 = 0; j2 < 8; ++j2)
        Vsm[(cc + j2)*72 + key] = vv[j2];
    }
    __syncthreads();

    // S = Q K^T  (rows fq*4+j, cols n*16+fr)
    f32x4 s[4] = {};
#pragma unroll
    for (int kk = 0; kk < 4; ++kk)
#pragma unroll
      for (int n = 0; n < 4; ++n) {
        bf16x8 kf = *reinterpret_cast<const bf16x8*>(Ksm + (n*16 + fr)*136 + kk*32 + fq*8);
        s[n] = __builtin_amdgcn_mfma_f32_16x16x32_bf16(qf[kk], kf, s[n], 0, 0, 0);
      }

    // online softmax (log2 domain; scale folded into q)
    float corr[4];
#pragma unroll
    for (int j = 0; j < 4; ++j) {
      float t = fmaxf(fmaxf(s[0][j], s[1][j]), fmaxf(s[2][j], s[3][j]));
      t = fmaxf(t, __shfl_xor(t, 1, 64));
      t = fmaxf(t, __shfl_xor(t, 2, 64));
      t = fmaxf(t, __shfl_xor(t, 4, 64));
      t = fmaxf(t, __shfl_xor(t, 8, 64));
      float mn = fmaxf(mrow[j], t);
      corr[j] = fexp2(mrow[j] - mn);
      float sum = 0.0f;
#pragma unroll
      for (int n = 0; n < 4; ++n) {
        float pv = fexp2(s[n][j] - mn);
        s[n][j] = pv;
        sum += pv;
      }
      sum += __shfl_xor(sum, 1, 64);
      sum += __shfl_xor(sum, 2, 64);
      sum += __shfl_xor(sum, 4, 64);
      sum += __shfl_xor(sum, 8, 64);
      lrow[j] = lrow[j]*corr[j] + sum;
      mrow[j] = mn;
    }
#pragma unroll
    for (int nn = 0; nn < 8; ++nn)
#pragma unroll
      for (int j = 0; j < 4; ++j)
        o[nn][j] *= corr[j];

    // P -> LDS (bf16), wave-local region
#pragma unroll
    for (int n = 0; n < 4; ++n)
#pragma unroll
      for (int j = 0; j < 4; ++j)
        Psm[(w*16 + fq*4 + j)*72 + n*16 + fr] = f2b(s[n][j]);
    __syncthreads();

    // O += P * V
#pragma unroll
    for (int kk2 = 0; kk2 < 2; ++kk2) {
      bf16x8 pf = *reinterpret_cast<const bf16x8*>(Psm + (w*16 + fr)*72 + kk2*32 + fq*8);
#pragma unroll
      for (int nn = 0; nn < 8; ++nn) {
        bf16x8 vf = *reinterpret_cast<const bf16x8*>(Vsm + (nn*16 + fr)*72 + kk2*32 + fq*8);
        o[nn] = __builtin_amdgcn_mfma_f32_16x16x32_bf16(pf, vf, o[nn], 0, 0, 0);
      }
    }
  }

  // epilogue: write bf16 to (b,l)-major [4096][3072] at col h*128
  const int b = bh / NH, h = bh % NH;
  u16* op = ob + (size_t)b * SL * DM + (size_t)h * HD;
#pragma unroll
  for (int nn = 0; nn < 8; ++nn)
#pragma unroll
    for (int j = 0; j < 4; ++j) {
      int r = q0 + w*16 + fq*4 + j;
      op[(size_t)r*DM + nn*16 + fr] = f2b(o[nn][j] / lrow[j]);
    }
}

extern "C" void kernel_launch(void* const* d_in, const int* in_sizes, int n_in,
                              void* d_out, int out_size, void* d_ws, size_t ws_size,
                              hipStream_t stream) {
  const float* x       = (const float*)d_in[0];
  const float* qkv_w   = (const float*)d_in[1];
  const float* q_scale = (const float*)d_in[2];
  const float* k_scale = (const float*)d_in[3];
  const float* proj_w  = (const float*)d_in[4];
  float* y = (float*)d_out;

  // workspace layout (u16 elems), with reuse:
  //  A: x_bf16 [4096*3072]  -> reused as attention output obuf
  //  B: qkv_w bf16 [9216*3072] -> reused for proj_w bf16
  //  C/D/E: q/k/v (B,H,L,Hd) bf16
  u16* regA = (u16*)d_ws;
  u16* regB = regA + (size_t)MM*DM;
  u16* qbuf = regB + (size_t)NE*DM;
  u16* kbuf = qbuf + (size_t)NB*NH*SL*HD;
  u16* vbuf = kbuf + (size_t)NB*NH*SL*HD;

  const int n4x = MM*DM/4, n4w = NE*DM/4, n4p = DM*DM/4;
  cvt_kernel<<<dim3((n4x + 255)/256), 256, 0, stream>>>(x, regA, n4x);
  cvt_kernel<<<dim3((n4w + 255)/256), 256, 0, stream>>>(qkv_w, regB, n4w);

  gemm_qkv<<<dim3(MM/128, NE/128), 256, 0, stream>>>(regA, regB, qbuf, kbuf, vbuf);

  const float QS = 1.4426950408889634f / 11.313708498984761f;  // log2(e)/sqrt(128)
  rmsnorm_k<<<dim3(NB*NH*SL/4), 256, 0, stream>>>(qbuf, q_scale, QS);
  rmsnorm_k<<<dim3(NB*NH*SL/4), 256, 0, stream>>>(kbuf, k_scale, 1.0f);

  // proj_w convert into regB (qkv_w bf16 dead after gemm_qkv; stream-ordered)
  cvt_kernel<<<dim3((n4p + 255)/256), 256, 0, stream>>>(proj_w, regB, n4p);

  // attention output into regA (x_bf16 dead after gemm_qkv)
  attn_kernel<<<dim3(SL/64, NB*NH), 256, 0, stream>>>(qbuf, kbuf, vbuf, regA);

  gemm_proj<<<dim3(MM/128, DM/128), 256, 0, stream>>>(regA, regB, y);
}

// Round 4
// 927.985 us; speedup vs baseline: 1.2621x; 1.2621x over previous
//
#include <hip/hip_runtime.h>

typedef unsigned short u16;
typedef unsigned int u32;
typedef __bf16 bf16x8 __attribute__((ext_vector_type(8)));
typedef u16 u16x8 __attribute__((ext_vector_type(8)));
typedef float f32x4 __attribute__((ext_vector_type(4)));

#define NH 24
#define SL 2048
#define DM 3072
#define HD 128
#define NB 2
#define MM (NB*SL)   // 4096
#define NE (3*DM)    // 9216

__device__ __forceinline__ float b2f(u16 u) { return __builtin_bit_cast(float, (u32)u << 16); }
__device__ __forceinline__ u16 f2b(float f) {
  u32 x = __builtin_bit_cast(u32, f);
  return (u16)((x + 0x7fffu + ((x >> 16) & 1u)) >> 16);   // RNE
}
__device__ __forceinline__ float fexp2(float x) {
#if __has_builtin(__builtin_amdgcn_exp2f)
  return __builtin_amdgcn_exp2f(x);
#else
  return exp2f(x);
#endif
}

__device__ __forceinline__ void stage16(const u16* g, u16* l, int lane) {
#if __has_builtin(__builtin_amdgcn_global_load_lds)
  // LDS dest is wave-uniform base; lane i's 16B land at l + i*16B.
  __builtin_amdgcn_global_load_lds((const __attribute__((address_space(1))) void*)g,
                                   (__attribute__((address_space(3))) void*)l, 16, 0, 0);
#else
  reinterpret_cast<u16x8*>(l)[lane] = *reinterpret_cast<const u16x8*>(g);
#endif
}

// ---------------- fp32 -> bf16 bulk convert ----------------
__global__ __launch_bounds__(256) void cvt_kernel(const float* __restrict__ src,
                                                  u16* __restrict__ dst, int n4) {
  int i = blockIdx.x * 256 + threadIdx.x;
  if (i >= n4) return;
  float4 v = reinterpret_cast<const float4*>(src)[i];
  u32 lo = (u32)f2b(v.x) | ((u32)f2b(v.y) << 16);
  u32 hi = (u32)f2b(v.z) | ((u32)f2b(v.w) << 16);
  reinterpret_cast<uint2*>(dst)[i] = make_uint2(lo, hi);
}

// ---------------- QKV GEMM: C = A * B^T -> scatter to q/k/v (B,H,L,Hd) bf16 ----------------
// A: [4096][3072] bf16, Bw: [9216][3072] bf16. 128x128 tile, BK=32, 4 waves (2x2 of 64x64).
__global__ __launch_bounds__(256) void gemm_qkv(const u16* __restrict__ A, const u16* __restrict__ Bw,
                                                u16* __restrict__ qb, u16* __restrict__ kb,
                                                u16* __restrict__ vb) {
  __shared__ __align__(16) u16 Asm[128*32];
  __shared__ __align__(16) u16 Bsm[128*32];
  const int tid = threadIdx.x;
  const int w = tid >> 6, lane = tid & 63;
  const int fq = lane >> 4, fr = lane & 15;
  const int wr = w >> 1, wc = w & 1;
  const int m0 = blockIdx.x * 128;
  const int e0 = blockIdx.y * 128;
  const int K = DM;
  const int c0 = 2*w, c1 = 2*w + 1;
  const int row0 = lane >> 2;           // 0..15 within 16-row chunk
  const int koff = (lane & 3) * 8;      // bf16 elems within 32-wide k

  f32x4 acc[4][4] = {};

  for (int kt = 0; kt < K; kt += 32) {
    __syncthreads();
    stage16(A + (size_t)(m0 + c0*16 + row0)*K + kt + koff, Asm + c0*512, lane);
    stage16(A + (size_t)(m0 + c1*16 + row0)*K + kt + koff, Asm + c1*512, lane);
    stage16(Bw + (size_t)(e0 + c0*16 + row0)*K + kt + koff, Bsm + c0*512, lane);
    stage16(Bw + (size_t)(e0 + c1*16 + row0)*K + kt + koff, Bsm + c1*512, lane);
    __syncthreads();   // compiler drains vmcnt before s_barrier
    bf16x8 af[4], bfr[4];
#pragma unroll
    for (int m = 0; m < 4; ++m)
      af[m] = *reinterpret_cast<const bf16x8*>(Asm + (wr*64 + m*16 + fr)*32 + fq*8);
#pragma unroll
    for (int n = 0; n < 4; ++n)
      bfr[n] = *reinterpret_cast<const bf16x8*>(Bsm + (wc*64 + n*16 + fr)*32 + fq*8);
#pragma unroll
    for (int m = 0; m < 4; ++m)
#pragma unroll
      for (int n = 0; n < 4; ++n)
        acc[m][n] = __builtin_amdgcn_mfma_f32_16x16x32_bf16(af[m], bfr[n], acc[m][n], 0, 0, 0);
  }

  // epilogue: tile cols e0..e0+127 are exactly one (s,h) head (e0 % 128 == 0)
  const int s = e0 / DM;
  const int h = (e0 % DM) >> 7;
  const int b = m0 >> 11;
  const int l0 = m0 & (SL - 1);
  u16* outb = (s == 0) ? qb : (s == 1) ? kb : vb;
  outb += ((size_t)(b*NH + h)*SL + l0) * HD;
#pragma unroll
  for (int m = 0; m < 4; ++m)
#pragma unroll
    for (int n = 0; n < 4; ++n)
#pragma unroll
      for (int j = 0; j < 4; ++j) {
        int rr = wr*64 + m*16 + fq*4 + j;
        int cc = wc*64 + n*16 + fr;
        outb[(size_t)rr*HD + cc] = f2b(acc[m][n][j]);
      }
}

// ---------------- proj GEMM: Y(fp32) = A * B^T ----------------
__global__ __launch_bounds__(256) void gemm_proj(const u16* __restrict__ A, const u16* __restrict__ Bw,
                                                 float* __restrict__ Y) {
  __shared__ __align__(16) u16 Asm[128*32];
  __shared__ __align__(16) u16 Bsm[128*32];
  const int tid = threadIdx.x;
  const int w = tid >> 6, lane = tid & 63;
  const int fq = lane >> 4, fr = lane & 15;
  const int wr = w >> 1, wc = w & 1;
  const int m0 = blockIdx.x * 128;
  const int e0 = blockIdx.y * 128;
  const int K = DM;
  const int c0 = 2*w, c1 = 2*w + 1;
  const int row0 = lane >> 2;
  const int koff = (lane & 3) * 8;

  f32x4 acc[4][4] = {};

  for (int kt = 0; kt < K; kt += 32) {
    __syncthreads();
    stage16(A + (size_t)(m0 + c0*16 + row0)*K + kt + koff, Asm + c0*512, lane);
    stage16(A + (size_t)(m0 + c1*16 + row0)*K + kt + koff, Asm + c1*512, lane);
    stage16(Bw + (size_t)(e0 + c0*16 + row0)*K + kt + koff, Bsm + c0*512, lane);
    stage16(Bw + (size_t)(e0 + c1*16 + row0)*K + kt + koff, Bsm + c1*512, lane);
    __syncthreads();
    bf16x8 af[4], bfr[4];
#pragma unroll
    for (int m = 0; m < 4; ++m)
      af[m] = *reinterpret_cast<const bf16x8*>(Asm + (wr*64 + m*16 + fr)*32 + fq*8);
#pragma unroll
    for (int n = 0; n < 4; ++n)
      bfr[n] = *reinterpret_cast<const bf16x8*>(Bsm + (wc*64 + n*16 + fr)*32 + fq*8);
#pragma unroll
    for (int m = 0; m < 4; ++m)
#pragma unroll
      for (int n = 0; n < 4; ++n)
        acc[m][n] = __builtin_amdgcn_mfma_f32_16x16x32_bf16(af[m], bfr[n], acc[m][n], 0, 0, 0);
  }

  float* y = Y + (size_t)m0*DM + e0;
#pragma unroll
  for (int m = 0; m < 4; ++m)
#pragma unroll
    for (int n = 0; n < 4; ++n)
#pragma unroll
      for (int j = 0; j < 4; ++j) {
        int rr = wr*64 + m*16 + fq*4 + j;
        int cc = wc*64 + n*16 + fr;
        y[(size_t)rr*DM + cc] = acc[m][n][j];
      }
}

// ---------------- RMSNorm over Hd=128, in place, one wave per row ----------------
__global__ __launch_bounds__(256) void rmsnorm_k(u16* __restrict__ buf, const float* __restrict__ scale,
                                                 float extra) {
  int row = blockIdx.x * 4 + (threadIdx.x >> 6);
  int lane = threadIdx.x & 63;
  u16* p = buf + (size_t)row * HD + lane * 2;
  u32 u = *reinterpret_cast<const u32*>(p);
  float a = b2f((u16)(u & 0xffffu));
  float c = b2f((u16)(u >> 16));
  float ss = a*a + c*c;
#pragma unroll
  for (int m = 32; m; m >>= 1) ss += __shfl_xor(ss, m, 64);
  float rr = rsqrtf(ss * (1.0f/128.0f) + 1e-6f);
  float s0 = scale[lane*2] * extra;
  float s1 = scale[lane*2 + 1] * extra;
  u32 o = (u32)f2b(a*rr*s0) | ((u32)f2b(c*rr*s1) << 16);
  *reinterpret_cast<u32*>(p) = o;
}

// ---------------- flash attention fwd, non-causal ----------------
// grid (L/64, B*H), 4 waves; wave w owns q rows [q0+w*16, +16). KV tile = 64.
// q is pre-scaled by q_scale * log2(e)/sqrt(128); k by k_scale. exp via exp2.
//
// V is stored TRANSPOSED in LDS ([hd][key], stride 72) with an XOR column
// swizzle: V[key][d] lives at Vsm[d*72 + (key ^ (((d>>3)&7)<<3))].
// Rationale: the un-swizzled transpose store had all 16 lanes of each
// quarter-wave at stride 8*72 u16 = 288 words = 0 mod 32 -> one bank,
// ~32-way conflict (2.15e8 SQ_LDS_BANK_CONFLICT, ~60% of kernel time).
// The XOR term varies with (d>>3)&7 across lanes -> 8 distinct banks.
// Reads XOR the 8-aligned key-block base with the same involution, so each
// bf16x8 stays contiguous (keys K0..K0+7 in order) and 16B-aligned, and the
// read's uniform bank-quad distribution is unchanged.
__global__ __launch_bounds__(256) void attn_kernel(const u16* __restrict__ qb, const u16* __restrict__ kb,
                                                   const u16* __restrict__ vb, u16* __restrict__ ob) {
  __shared__ __align__(16) u16 Ksm[64*136];   // [key][hd], padded stride 136
  __shared__ __align__(16) u16 Vsm[128*72];   // transposed [hd][key-swizzled], stride 72
  __shared__ __align__(16) u16 Psm[64*72];    // [qrow][key], stride 72
  const int tid = threadIdx.x;
  const int w = tid >> 6, lane = tid & 63;
  const int fq = lane >> 4, fr = lane & 15;
  const int bh = blockIdx.y;
  const int q0 = blockIdx.x * 64;
  const u16* qrow = qb + (size_t)bh * SL * HD;
  const u16* krow = kb + (size_t)bh * SL * HD;
  const u16* vrow = vb + (size_t)bh * SL * HD;

  // Q fragments in registers: rows q0 + w*16 + fr, 4 k-chunks of 32
  bf16x8 qf[4];
#pragma unroll
  for (int kk = 0; kk < 4; ++kk)
    qf[kk] = *reinterpret_cast<const bf16x8*>(qrow + (size_t)(q0 + w*16 + fr)*HD + kk*32 + fq*8);

  f32x4 o[8] = {};           // 8 hd-tiles of 16
  float mrow[4], lrow[4];
#pragma unroll
  for (int j = 0; j < 4; ++j) { mrow[j] = -1e30f; lrow[j] = 0.0f; }

  for (int kt = 0; kt < SL; kt += 64) {
    __syncthreads();         // prev iter's PV reads done before restage
    // stage K (row-major, padded) and V (transposed + XOR-swizzled)
    for (int c = tid; c < 1024; c += 256) {
      int key = c >> 4;
      int cc = (c & 15) * 8;
      *reinterpret_cast<bf16x8*>(Ksm + key*136 + cc) =
          *reinterpret_cast<const bf16x8*>(krow + (size_t)(kt + key)*HD + cc);
      u16x8 vv = *reinterpret_cast<const u16x8*>(vrow + (size_t)(kt + key)*HD + cc);
      int skey = key ^ ((cc >> 3) & 7) << 3;   // d>>3 == cc>>3 for all 8 elems (cc % 8 == 0)
#pragma unroll
      for (int j2 = 0; j2 < 8; ++j2)
        Vsm[(cc + j2)*72 + skey] = vv[j2];
    }
    __syncthreads();

    // S = Q K^T  (rows fq*4+j, cols n*16+fr)
    f32x4 s[4] = {};
#pragma unroll
    for (int kk = 0; kk < 4; ++kk)
#pragma unroll
      for (int n = 0; n < 4; ++n) {
        bf16x8 kf = *reinterpret_cast<const bf16x8*>(Ksm + (n*16 + fr)*136 + kk*32 + fq*8);
        s[n] = __builtin_amdgcn_mfma_f32_16x16x32_bf16(qf[kk], kf, s[n], 0, 0, 0);
      }

    // online softmax (log2 domain; scale folded into q)
    float corr[4];
#pragma unroll
    for (int j = 0; j < 4; ++j) {
      float t = fmaxf(fmaxf(s[0][j], s[1][j]), fmaxf(s[2][j], s[3][j]));
      t = fmaxf(t, __shfl_xor(t, 1, 64));
      t = fmaxf(t, __shfl_xor(t, 2, 64));
      t = fmaxf(t, __shfl_xor(t, 4, 64));
      t = fmaxf(t, __shfl_xor(t, 8, 64));
      float mn = fmaxf(mrow[j], t);
      corr[j] = fexp2(mrow[j] - mn);
      float sum = 0.0f;
#pragma unroll
      for (int n = 0; n < 4; ++n) {
        float pv = fexp2(s[n][j] - mn);
        s[n][j] = pv;
        sum += pv;
      }
      sum += __shfl_xor(sum, 1, 64);
      sum += __shfl_xor(sum, 2, 64);
      sum += __shfl_xor(sum, 4, 64);
      sum += __shfl_xor(sum, 8, 64);
      lrow[j] = lrow[j]*corr[j] + sum;
      mrow[j] = mn;
    }
#pragma unroll
    for (int nn = 0; nn < 8; ++nn)
#pragma unroll
      for (int j = 0; j < 4; ++j)
        o[nn][j] *= corr[j];

    // P -> LDS (bf16), wave-local region
#pragma unroll
    for (int n = 0; n < 4; ++n)
#pragma unroll
      for (int j = 0; j < 4; ++j)
        Psm[(w*16 + fq*4 + j)*72 + n*16 + fr] = f2b(s[n][j]);
    __syncthreads();

    // O += P * V
#pragma unroll
    for (int kk2 = 0; kk2 < 2; ++kk2) {
      bf16x8 pf = *reinterpret_cast<const bf16x8*>(Psm + (w*16 + fr)*72 + kk2*32 + fq*8);
#pragma unroll
      for (int nn = 0; nn < 8; ++nn) {
        int row = nn*16 + fr;
        int xr = ((row >> 3) & 7) << 3;
        bf16x8 vf = *reinterpret_cast<const bf16x8*>(Vsm + row*72 + ((kk2*32 + fq*8) ^ xr));
        o[nn] = __builtin_amdgcn_mfma_f32_16x16x32_bf16(pf, vf, o[nn], 0, 0, 0);
      }
    }
  }

  // epilogue: write bf16 to (b,l)-major [4096][3072] at col h*128
  const int b = bh / NH, h = bh % NH;
  u16* op = ob + (size_t)b * SL * DM + (size_t)h * HD;
#pragma unroll
  for (int nn = 0; nn < 8; ++nn)
#pragma unroll
    for (int j = 0; j < 4; ++j) {
      int r = q0 + w*16 + fq*4 + j;
      op[(size_t)r*DM + nn*16 + fr] = f2b(o[nn][j] / lrow[j]);
    }
}

extern "C" void kernel_launch(void* const* d_in, const int* in_sizes, int n_in,
                              void* d_out, int out_size, void* d_ws, size_t ws_size,
                              hipStream_t stream) {
  const float* x       = (const float*)d_in[0];
  const float* qkv_w   = (const float*)d_in[1];
  const float* q_scale = (const float*)d_in[2];
  const float* k_scale = (const float*)d_in[3];
  const float* proj_w  = (const float*)d_in[4];
  float* y = (float*)d_out;

  // workspace layout (u16 elems), with reuse:
  //  A: x_bf16 [4096*3072]  -> reused as attention output obuf
  //  B: qkv_w bf16 [9216*3072] -> reused for proj_w bf16
  //  C/D/E: q/k/v (B,H,L,Hd) bf16
  u16* regA = (u16*)d_ws;
  u16* regB = regA + (size_t)MM*DM;
  u16* qbuf = regB + (size_t)NE*DM;
  u16* kbuf = qbuf + (size_t)NB*NH*SL*HD;
  u16* vbuf = kbuf + (size_t)NB*NH*SL*HD;

  const int n4x = MM*DM/4, n4w = NE*DM/4, n4p = DM*DM/4;
  cvt_kernel<<<dim3((n4x + 255)/256), 256, 0, stream>>>(x, regA, n4x);
  cvt_kernel<<<dim3((n4w + 255)/256), 256, 0, stream>>>(qkv_w, regB, n4w);

  gemm_qkv<<<dim3(MM/128, NE/128), 256, 0, stream>>>(regA, regB, qbuf, kbuf, vbuf);

  const float QS = 1.4426950408889634f / 11.313708498984761f;  // log2(e)/sqrt(128)
  rmsnorm_k<<<dim3(NB*NH*SL/4), 256, 0, stream>>>(qbuf, q_scale, QS);
  rmsnorm_k<<<dim3(NB*NH*SL/4), 256, 0, stream>>>(kbuf, k_scale, 1.0f);

  // proj_w convert into regB (qkv_w bf16 dead after gemm_qkv; stream-ordered)
  cvt_kernel<<<dim3((n4p + 255)/256), 256, 0, stream>>>(proj_w, regB, n4p);

  // attention output into regA (x_bf16 dead after gemm_qkv)
  attn_kernel<<<dim3(SL/64, NB*NH), 256, 0, stream>>>(qbuf, kbuf, vbuf, regA);

  gemm_proj<<<dim3(MM/128, DM/128), 256, 0, stream>>>(regA, regB, y);
}

// Round 6
// 901.964 us; speedup vs baseline: 1.2985x; 1.0288x over previous
//
#include <hip/hip_runtime.h>

typedef unsigned short u16;
typedef unsigned int u32;
typedef __bf16 bf16x8 __attribute__((ext_vector_type(8)));
typedef u16 u16x8 __attribute__((ext_vector_type(8)));
typedef float f32x4 __attribute__((ext_vector_type(4)));

#define NH 24
#define SL 2048
#define DM 3072
#define HD 128
#define NB 2
#define MM (NB*SL)   // 4096
#define NE (3*DM)    // 9216

__device__ __forceinline__ float b2f(u16 u) { return __builtin_bit_cast(float, (u32)u << 16); }
__device__ __forceinline__ u16 f2b(float f) {
  u32 x = __builtin_bit_cast(u32, f);
  return (u16)((x + 0x7fffu + ((x >> 16) & 1u)) >> 16);   // RNE
}
__device__ __forceinline__ float fexp2(float x) {
#if __has_builtin(__builtin_amdgcn_exp2f)
  return __builtin_amdgcn_exp2f(x);
#else
  return exp2f(x);
#endif
}

__device__ __forceinline__ void stage16(const u16* g, u16* l, int lane) {
#if __has_builtin(__builtin_amdgcn_global_load_lds)
  // LDS dest is wave-uniform base; lane i's 16B land at l + i*16B.
  __builtin_amdgcn_global_load_lds((const __attribute__((address_space(1))) void*)g,
                                   (__attribute__((address_space(3))) void*)l, 16, 0, 0);
#else
  reinterpret_cast<u16x8*>(l)[lane] = *reinterpret_cast<const u16x8*>(g);
#endif
}

// XCD-aware bijective block swizzle (T1): original dispatch slot i lands on
// XCD i%8; give that XCD the contiguous work chunk [(i%8)*nwg/8 ...).
// Requires nwg % 8 == 0 (qkv: 2304, proj: 768 — both OK).
__device__ __forceinline__ int xcd_swz(int lin, int nwg) {
  int cpx = nwg >> 3;
  return (lin & 7) * cpx + (lin >> 3);
}

// ---------------- fp32 -> bf16 bulk convert ----------------
__global__ __launch_bounds__(256) void cvt_kernel(const float* __restrict__ src,
                                                  u16* __restrict__ dst, int n4) {
  int i = blockIdx.x * 256 + threadIdx.x;
  if (i >= n4) return;
  float4 v = reinterpret_cast<const float4*>(src)[i];
  u32 lo = (u32)f2b(v.x) | ((u32)f2b(v.y) << 16);
  u32 hi = (u32)f2b(v.z) | ((u32)f2b(v.w) << 16);
  reinterpret_cast<uint2*>(dst)[i] = make_uint2(lo, hi);
}

// ---------------- QKV GEMM: C = A * B^T -> scatter to q/k/v (B,H,L,Hd) bf16 ----------------
// A: [4096][3072] bf16, Bw: [9216][3072] bf16. 128x128 tile, BK=32, 4 waves (2x2 of 64x64).
__global__ __launch_bounds__(256) void gemm_qkv(const u16* __restrict__ A, const u16* __restrict__ Bw,
                                                u16* __restrict__ qb, u16* __restrict__ kb,
                                                u16* __restrict__ vb) {
  __shared__ __align__(16) u16 Asm[128*32];
  __shared__ __align__(16) u16 Bsm[128*32];
  const int tid = threadIdx.x;
  const int w = tid >> 6, lane = tid & 63;
  const int fq = lane >> 4, fr = lane & 15;
  const int wr = w >> 1, wc = w & 1;
  // XCD swizzle: linear id x-fastest; chunk of consecutive-x blocks (shared
  // B-tile) stays on one XCD's L2.
  const int nwg = gridDim.x * gridDim.y;
  const int swz = xcd_swz(blockIdx.y * gridDim.x + blockIdx.x, nwg);
  const int m0 = (swz % gridDim.x) * 128;
  const int e0 = (swz / gridDim.x) * 128;
  const int K = DM;
  const int c0 = 2*w, c1 = 2*w + 1;
  const int row0 = lane >> 2;           // 0..15 within 16-row chunk
  const int koff = (lane & 3) * 8;      // bf16 elems within 32-wide k

  f32x4 acc[4][4] = {};

  for (int kt = 0; kt < K; kt += 32) {
    __syncthreads();
    stage16(A + (size_t)(m0 + c0*16 + row0)*K + kt + koff, Asm + c0*512, lane);
    stage16(A + (size_t)(m0 + c1*16 + row0)*K + kt + koff, Asm + c1*512, lane);
    stage16(Bw + (size_t)(e0 + c0*16 + row0)*K + kt + koff, Bsm + c0*512, lane);
    stage16(Bw + (size_t)(e0 + c1*16 + row0)*K + kt + koff, Bsm + c1*512, lane);
    __syncthreads();   // compiler drains vmcnt before s_barrier
    bf16x8 af[4], bfr[4];
#pragma unroll
    for (int m = 0; m < 4; ++m)
      af[m] = *reinterpret_cast<const bf16x8*>(Asm + (wr*64 + m*16 + fr)*32 + fq*8);
#pragma unroll
    for (int n = 0; n < 4; ++n)
      bfr[n] = *reinterpret_cast<const bf16x8*>(Bsm + (wc*64 + n*16 + fr)*32 + fq*8);
#pragma unroll
    for (int m = 0; m < 4; ++m)
#pragma unroll
      for (int n = 0; n < 4; ++n)
        acc[m][n] = __builtin_amdgcn_mfma_f32_16x16x32_bf16(af[m], bfr[n], acc[m][n], 0, 0, 0);
  }

  // epilogue: tile cols e0..e0+127 are exactly one (s,h) head (e0 % 128 == 0)
  const int s = e0 / DM;
  const int h = (e0 % DM) >> 7;
  const int b = m0 >> 11;
  const int l0 = m0 & (SL - 1);
  u16* outb = (s == 0) ? qb : (s == 1) ? kb : vb;
  outb += ((size_t)(b*NH + h)*SL + l0) * HD;
#pragma unroll
  for (int m = 0; m < 4; ++m)
#pragma unroll
    for (int n = 0; n < 4; ++n)
#pragma unroll
      for (int j = 0; j < 4; ++j) {
        int rr = wr*64 + m*16 + fq*4 + j;
        int cc = wc*64 + n*16 + fr;
        outb[(size_t)rr*HD + cc] = f2b(acc[m][n][j]);
      }
}

// ---------------- proj GEMM: Y(fp32) = A * B^T ----------------
__global__ __launch_bounds__(256) void gemm_proj(const u16* __restrict__ A, const u16* __restrict__ Bw,
                                                 float* __restrict__ Y) {
  __shared__ __align__(16) u16 Asm[128*32];
  __shared__ __align__(16) u16 Bsm[128*32];
  const int tid = threadIdx.x;
  const int w = tid >> 6, lane = tid & 63;
  const int fq = lane >> 4, fr = lane & 15;
  const int wr = w >> 1, wc = w & 1;
  const int nwg = gridDim.x * gridDim.y;
  const int swz = xcd_swz(blockIdx.y * gridDim.x + blockIdx.x, nwg);
  const int m0 = (swz % gridDim.x) * 128;
  const int e0 = (swz / gridDim.x) * 128;
  const int K = DM;
  const int c0 = 2*w, c1 = 2*w + 1;
  const int row0 = lane >> 2;
  const int koff = (lane & 3) * 8;

  f32x4 acc[4][4] = {};

  for (int kt = 0; kt < K; kt += 32) {
    __syncthreads();
    stage16(A + (size_t)(m0 + c0*16 + row0)*K + kt + koff, Asm + c0*512, lane);
    stage16(A + (size_t)(m0 + c1*16 + row0)*K + kt + koff, Asm + c1*512, lane);
    stage16(Bw + (size_t)(e0 + c0*16 + row0)*K + kt + koff, Bsm + c0*512, lane);
    stage16(Bw + (size_t)(e0 + c1*16 + row0)*K + kt + koff, Bsm + c1*512, lane);
    __syncthreads();
    bf16x8 af[4], bfr[4];
#pragma unroll
    for (int m = 0; m < 4; ++m)
      af[m] = *reinterpret_cast<const bf16x8*>(Asm + (wr*64 + m*16 + fr)*32 + fq*8);
#pragma unroll
    for (int n = 0; n < 4; ++n)
      bfr[n] = *reinterpret_cast<const bf16x8*>(Bsm + (wc*64 + n*16 + fr)*32 + fq*8);
#pragma unroll
    for (int m = 0; m < 4; ++m)
#pragma unroll
      for (int n = 0; n < 4; ++n)
        acc[m][n] = __builtin_amdgcn_mfma_f32_16x16x32_bf16(af[m], bfr[n], acc[m][n], 0, 0, 0);
  }

  float* y = Y + (size_t)m0*DM + e0;
#pragma unroll
  for (int m = 0; m < 4; ++m)
#pragma unroll
    for (int n = 0; n < 4; ++n)
#pragma unroll
      for (int j = 0; j < 4; ++j) {
        int rr = wr*64 + m*16 + fq*4 + j;
        int cc = wc*64 + n*16 + fr;
        y[(size_t)rr*DM + cc] = acc[m][n][j];
      }
}

// ---------------- RMSNorm over Hd=128, in place, one wave per row ----------------
__global__ __launch_bounds__(256) void rmsnorm_k(u16* __restrict__ buf, const float* __restrict__ scale,
                                                 float extra) {
  int row = blockIdx.x * 4 + (threadIdx.x >> 6);
  int lane = threadIdx.x & 63;
  u16* p = buf + (size_t)row * HD + lane * 2;
  u32 u = *reinterpret_cast<const u32*>(p);
  float a = b2f((u16)(u & 0xffffu));
  float c = b2f((u16)(u >> 16));
  float ss = a*a + c*c;
#pragma unroll
  for (int m = 32; m; m >>= 1) ss += __shfl_xor(ss, m, 64);
  float rr = rsqrtf(ss * (1.0f/128.0f) + 1e-6f);
  float s0 = scale[lane*2] * extra;
  float s1 = scale[lane*2 + 1] * extra;
  u32 o = (u32)f2b(a*rr*s0) | ((u32)f2b(c*rr*s1) << 16);
  *reinterpret_cast<u32*>(p) = o;
}

// ---------------- flash attention fwd, non-causal ----------------
// grid (L/128, B*H), 8 waves (512 thr); wave w owns q rows [q0+w*16, +16).
// KV tile = 64. QBLK=128: staging (K b128 stores + V scalar transpose stores)
// is fixed cost per KV tile -> 2x q-rows per block halves staging per unit of
// attention work, and halves K/V HBM re-reads (16 q-blocks per head vs 32).
// q pre-scaled by q_scale*log2(e)/sqrt(128); k by k_scale. exp via exp2.
//
// V is stored TRANSPOSED in LDS ([hd][key], stride 72) with an XOR column
// swizzle: V[key][d] lives at Vsm[d*72 + (key ^ (((d>>3)&7)<<3))] (round-4
// verified: conflicts 2.15e8 -> 3.9e7, attn 580 -> 323 us).
__global__ __launch_bounds__(512) void attn_kernel(const u16* __restrict__ qb, const u16* __restrict__ kb,
                                                   const u16* __restrict__ vb, u16* __restrict__ ob) {
  __shared__ __align__(16) u16 Ksm[64*136];    // [key][hd], padded stride 136
  __shared__ __align__(16) u16 Vsm[128*72];    // transposed [hd][key-swizzled]
  __shared__ __align__(16) u16 Psm[128*72];    // [qrow][key], stride 72
  const int tid = threadIdx.x;
  const int w = tid >> 6, lane = tid & 63;
  const int fq = lane >> 4, fr = lane & 15;
  const int bh = blockIdx.y;
  const int q0 = blockIdx.x * 128;
  const u16* qrow = qb + (size_t)bh * SL * HD;
  const u16* krow = kb + (size_t)bh * SL * HD;
  const u16* vrow = vb + (size_t)bh * SL * HD;

  // Q fragments in registers: rows q0 + w*16 + fr, 4 k-chunks of 32
  bf16x8 qf[4];
#pragma unroll
  for (int kk = 0; kk < 4; ++kk)
    qf[kk] = *reinterpret_cast<const bf16x8*>(qrow + (size_t)(q0 + w*16 + fr)*HD + kk*32 + fq*8);

  f32x4 o[8] = {};           // 8 hd-tiles of 16
  float mrow[4], lrow[4];
#pragma unroll
  for (int j = 0; j < 4; ++j) { mrow[j] = -1e30f; lrow[j] = 0.0f; }

  for (int kt = 0; kt < SL; kt += 64) {
    __syncthreads();         // prev iter's PV reads done before restage
    // stage K (row-major, padded) and V (transposed + XOR-swizzled)
    for (int c = tid; c < 1024; c += 512) {
      int key = c >> 4;
      int cc = (c & 15) * 8;
      *reinterpret_cast<bf16x8*>(Ksm + key*136 + cc) =
          *reinterpret_cast<const bf16x8*>(krow + (size_t)(kt + key)*HD + cc);
      u16x8 vv = *reinterpret_cast<const u16x8*>(vrow + (size_t)(kt + key)*HD + cc);
      int skey = key ^ ((cc >> 3) & 7) << 3;   // d>>3 == cc>>3 for all 8 elems (cc % 8 == 0)
#pragma unroll
      for (int j2 = 0; j2 < 8; ++j2)
        Vsm[(cc + j2)*72 + skey] = vv[j2];
    }
    __syncthreads();

    // S = Q K^T  (rows fq*4+j, cols n*16+fr)
    f32x4 s[4] = {};
#pragma unroll
    for (int kk = 0; kk < 4; ++kk)
#pragma unroll
      for (int n = 0; n < 4; ++n) {
        bf16x8 kf = *reinterpret_cast<const bf16x8*>(Ksm + (n*16 + fr)*136 + kk*32 + fq*8);
        s[n] = __builtin_amdgcn_mfma_f32_16x16x32_bf16(qf[kk], kf, s[n], 0, 0, 0);
      }

    // online softmax (log2 domain; scale folded into q)
    float corr[4];
#pragma unroll
    for (int j = 0; j < 4; ++j) {
      float t = fmaxf(fmaxf(s[0][j], s[1][j]), fmaxf(s[2][j], s[3][j]));
      t = fmaxf(t, __shfl_xor(t, 1, 64));
      t = fmaxf(t, __shfl_xor(t, 2, 64));
      t = fmaxf(t, __shfl_xor(t, 4, 64));
      t = fmaxf(t, __shfl_xor(t, 8, 64));
      float mn = fmaxf(mrow[j], t);
      corr[j] = fexp2(mrow[j] - mn);
      float sum = 0.0f;
#pragma unroll
      for (int n = 0; n < 4; ++n) {
        float pv = fexp2(s[n][j] - mn);
        s[n][j] = pv;
        sum += pv;
      }
      sum += __shfl_xor(sum, 1, 64);
      sum += __shfl_xor(sum, 2, 64);
      sum += __shfl_xor(sum, 4, 64);
      sum += __shfl_xor(sum, 8, 64);
      lrow[j] = lrow[j]*corr[j] + sum;
      mrow[j] = mn;
    }
#pragma unroll
    for (int nn = 0; nn < 8; ++nn)
#pragma unroll
      for (int j = 0; j < 4; ++j)
        o[nn][j] *= corr[j];

    // P -> LDS (bf16), wave-local region
#pragma unroll
    for (int n = 0; n < 4; ++n)
#pragma unroll
      for (int j = 0; j < 4; ++j)
        Psm[(w*16 + fq*4 + j)*72 + n*16 + fr] = f2b(s[n][j]);
    __syncthreads();

    // O += P * V
#pragma unroll
    for (int kk2 = 0; kk2 < 2; ++kk2) {
      bf16x8 pf = *reinterpret_cast<const bf16x8*>(Psm + (w*16 + fr)*72 + kk2*32 + fq*8);
#pragma unroll
      for (int nn = 0; nn < 8; ++nn) {
        int row = nn*16 + fr;
        int xr = ((row >> 3) & 7) << 3;
        bf16x8 vf = *reinterpret_cast<const bf16x8*>(Vsm + row*72 + ((kk2*32 + fq*8) ^ xr));
        o[nn] = __builtin_amdgcn_mfma_f32_16x16x32_bf16(pf, vf, o[nn], 0, 0, 0);
      }
    }
  }

  // epilogue: write bf16 to (b,l)-major [4096][3072] at col h*128
  const int b = bh / NH, h = bh % NH;
  u16* op = ob + (size_t)b * SL * DM + (size_t)h * HD;
#pragma unroll
  for (int nn = 0; nn < 8; ++nn)
#pragma unroll
    for (int j = 0; j < 4; ++j) {
      int r = q0 + w*16 + fq*4 + j;
      op[(size_t)r*DM + nn*16 + fr] = f2b(o[nn][j] / lrow[j]);
    }
}

extern "C" void kernel_launch(void* const* d_in, const int* in_sizes, int n_in,
                              void* d_out, int out_size, void* d_ws, size_t ws_size,
                              hipStream_t stream) {
  const float* x       = (const float*)d_in[0];
  const float* qkv_w   = (const float*)d_in[1];
  const float* q_scale = (const float*)d_in[2];
  const float* k_scale = (const float*)d_in[3];
  const float* proj_w  = (const float*)d_in[4];
  float* y = (float*)d_out;

  // workspace layout (u16 elems), with reuse:
  //  A: x_bf16 [4096*3072]  -> reused as attention output obuf
  //  B: qkv_w bf16 [9216*3072] -> reused for proj_w bf16
  //  C/D/E: q/k/v (B,H,L,Hd) bf16
  u16* regA = (u16*)d_ws;
  u16* regB = regA + (size_t)MM*DM;
  u16* qbuf = regB + (size_t)NE*DM;
  u16* kbuf = qbuf + (size_t)NB*NH*SL*HD;
  u16* vbuf = kbuf + (size_t)NB*NH*SL*HD;

  const int n4x = MM*DM/4, n4w = NE*DM/4, n4p = DM*DM/4;
  cvt_kernel<<<dim3((n4x + 255)/256), 256, 0, stream>>>(x, regA, n4x);
  cvt_kernel<<<dim3((n4w + 255)/256), 256, 0, stream>>>(qkv_w, regB, n4w);

  gemm_qkv<<<dim3(MM/128, NE/128), 256, 0, stream>>>(regA, regB, qbuf, kbuf, vbuf);

  const float QS = 1.4426950408889634f / 11.313708498984761f;  // log2(e)/sqrt(128)
  rmsnorm_k<<<dim3(NB*NH*SL/4), 256, 0, stream>>>(qbuf, q_scale, QS);
  rmsnorm_k<<<dim3(NB*NH*SL/4), 256, 0, stream>>>(kbuf, k_scale, 1.0f);

  // proj_w convert into regB (qkv_w bf16 dead after gemm_qkv; stream-ordered)
  cvt_kernel<<<dim3((n4p + 255)/256), 256, 0, stream>>>(proj_w, regB, n4p);

  // attention output into regA (x_bf16 dead after gemm_qkv)
  attn_kernel<<<dim3(SL/128, NB*NH), 512, 0, stream>>>(qbuf, kbuf, vbuf, regA);

  gemm_proj<<<dim3(MM/128, DM/128), 256, 0, stream>>>(regA, regB, y);
}

// Round 7
// 867.916 us; speedup vs baseline: 1.3494x; 1.0392x over previous
//
#include <hip/hip_runtime.h>

typedef unsigned short u16;
typedef unsigned int u32;
typedef __bf16 bf16x8 __attribute__((ext_vector_type(8)));
typedef u16 u16x8 __attribute__((ext_vector_type(8)));
typedef float f32x4 __attribute__((ext_vector_type(4)));

#define NH 24
#define SL 2048
#define DM 3072
#define HD 128
#define NB 2
#define MM (NB*SL)   // 4096
#define NE (3*DM)    // 9216

// GEMM geometry (round 7): 256x192 tile, BK=32, 8 waves (2M x 4N), dbuf LDS 56 KiB.
#define BM 256
#define BN 192
#define BK 32
#define NT (DM/BK)   // 96

__device__ __forceinline__ float b2f(u16 u) { return __builtin_bit_cast(float, (u32)u << 16); }
__device__ __forceinline__ u16 f2b(float f) {
  u32 x = __builtin_bit_cast(u32, f);
  return (u16)((x + 0x7fffu + ((x >> 16) & 1u)) >> 16);   // RNE
}
__device__ __forceinline__ float fexp2(float x) {
#if __has_builtin(__builtin_amdgcn_exp2f)
  return __builtin_amdgcn_exp2f(x);
#else
  return exp2f(x);
#endif
}

__device__ __forceinline__ void stage16(const u16* g, u16* l, int lane) {
#if __has_builtin(__builtin_amdgcn_global_load_lds)
  // LDS dest is wave-uniform base; lane i's 16B land at l + i*16B. Global src is per-lane.
  __builtin_amdgcn_global_load_lds((const __attribute__((address_space(1))) void*)g,
                                   (__attribute__((address_space(3))) void*)l, 16, 0, 0);
#else
  reinterpret_cast<u16x8*>(l)[lane] = *reinterpret_cast<const u16x8*>(g);
#endif
}

// XCD-aware bijective block swizzle (T1). Requires nwg % 8 == 0 (768 / 256: OK).
__device__ __forceinline__ int xcd_swz(int lin, int nwg) {
  int cpx = nwg >> 3;
  return (lin & 7) * cpx + (lin >> 3);
}

// ---------------- fp32 -> bf16 bulk convert ----------------
__global__ __launch_bounds__(256) void cvt_kernel(const float* __restrict__ src,
                                                  u16* __restrict__ dst, int n4) {
  int i = blockIdx.x * 256 + threadIdx.x;
  if (i >= n4) return;
  float4 v = reinterpret_cast<const float4*>(src)[i];
  u32 lo = (u32)f2b(v.x) | ((u32)f2b(v.y) << 16);
  u32 hi = (u32)f2b(v.z) | ((u32)f2b(v.w) << 16);
  reinterpret_cast<uint2*>(dst)[i] = make_uint2(lo, hi);
}

// ======================= 2-phase dbuf GEMM core (macro body) =======================
// LDS tiles are [row][32] bf16, row stride 64 B = 4 slots of 16 B.
// T2 swizzle: data of global (row, c16) lives at slot (c16 ^ (row&3)):
//   read  addr (u16): row*32 + ((c16 ^ (row&3)) << 3)
//   stage: lane l of chunk ch covers row = ch*16 + (l>>2), slot = l&3,
//          global c16 = (l&3) ^ ((l>>2)&3)  (pre-swizzled source, linear LDS dest).
// Per K-tile: ph0 {read B(3)+A-quad0(4); issue 7 stages for t+1 -> buf c^1; bar;
// prio1; 12 MFMA; prio0; bar}  ph1 {read A-quad1; bar; prio1; 12 MFMA; prio0};
// tile ends with __syncthreads() (vmcnt(0)+lgkm(0) drain publishes t+1's tiles;
// loads were issued ~2 phases earlier so the drain is effectively counted).

#define GEMM_STAGE(Aptr, Bptr, kt, Asd, Bsd)                                          \
  {                                                                                   \
    const int r_in = lane >> 2;                                                       \
    const int gcol = (((lane & 3) ^ (r_in & 3)) << 3);                                \
    _Pragma("unroll")                                                                 \
    for (int i = 0; i < 2; ++i) {                                                     \
      int ch = w + i * 8;                                                             \
      stage16(Aptr + (size_t)(m0 + ch * 16 + r_in) * DM + (kt) + gcol,                \
              (Asd) + ch * 512, lane);                                                \
    }                                                                                 \
    stage16(Bptr + (size_t)(e0 + w * 16 + r_in) * DM + (kt) + gcol,                   \
            (Bsd) + w * 512, lane);                                                   \
    if (w < 4)                                                                        \
      stage16(Bptr + (size_t)(e0 + (w + 8) * 16 + r_in) * DM + (kt) + gcol,           \
              (Bsd) + (w + 8) * 512, lane);                                           \
  }

#define GEMM_KLOOP(Aptr, Bptr)                                                        \
  f32x4 acc[8][3] = {};                                                               \
  GEMM_STAGE(Aptr, Bptr, 0, As[0], Bs[0]);                                            \
  __syncthreads();                                                                    \
  for (int t = 0; t < NT; ++t) {                                                      \
    const int c = t & 1;                                                              \
    const u16* Asc = As[c];                                                           \
    const u16* Bsc = Bs[c];                                                           \
    bf16x8 bfr[3], a0[4];                                                             \
    _Pragma("unroll")                                                                 \
    for (int n = 0; n < 3; ++n) {                                                     \
      int row = wc * 48 + n * 16 + fr;                                                \
      bfr[n] = *reinterpret_cast<const bf16x8*>(Bsc + row * 32 +                      \
                                                ((fq ^ (row & 3)) << 3));             \
    }                                                                                 \
    _Pragma("unroll")                                                                 \
    for (int m = 0; m < 4; ++m) {                                                     \
      int row = wr * 128 + m * 16 + fr;                                               \
      a0[m] = *reinterpret_cast<const bf16x8*>(Asc + row * 32 +                       \
                                               ((fq ^ (row & 3)) << 3));              \
    }                                                                                 \
    if (t + 1 < NT) { GEMM_STAGE(Aptr, Bptr, (t + 1) * BK, As[c ^ 1], Bs[c ^ 1]); }   \
    __builtin_amdgcn_s_barrier();                                                     \
    __builtin_amdgcn_sched_barrier(0);                                                \
    __builtin_amdgcn_s_setprio(1);                                                    \
    _Pragma("unroll")                                                                 \
    for (int m = 0; m < 4; ++m)                                                       \
      _Pragma("unroll")                                                               \
      for (int n = 0; n < 3; ++n)                                                     \
        acc[m][n] = __builtin_amdgcn_mfma_f32_16x16x32_bf16(a0[m], bfr[n],            \
                                                            acc[m][n], 0, 0, 0);     \
    __builtin_amdgcn_s_setprio(0);                                                    \
    __builtin_amdgcn_s_barrier();                                                     \
    __builtin_amdgcn_sched_barrier(0);                                                \
    _Pragma("unroll")                                                                 \
    for (int m = 0; m < 4; ++m) {                                                     \
      int row = wr * 128 + (m + 4) * 16 + fr;                                         \
      a0[m] = *reinterpret_cast<const bf16x8*>(Asc + row * 32 +                       \
                                               ((fq ^ (row & 3)) << 3));              \
    }                                                                                 \
    __builtin_amdgcn_s_barrier();                                                     \
    __builtin_amdgcn_sched_barrier(0);                                                \
    __builtin_amdgcn_s_setprio(1);                                                    \
    _Pragma("unroll")                                                                 \
    for (int m = 0; m < 4; ++m)                                                       \
      _Pragma("unroll")                                                               \
      for (int n = 0; n < 3; ++n)                                                     \
        acc[m + 4][n] = __builtin_amdgcn_mfma_f32_16x16x32_bf16(a0[m], bfr[n],        \
                                                                acc[m + 4][n],       \
                                                                0, 0, 0);             \
    __builtin_amdgcn_s_setprio(0);                                                    \
    __syncthreads();                                                                  \
  }

// ---------------- QKV GEMM: C = A * B^T -> scatter to q/k/v (B,H,L,Hd) bf16 --------
__global__ __launch_bounds__(512, 2) void gemm_qkv(const u16* __restrict__ A,
                                                   const u16* __restrict__ Bw,
                                                   u16* __restrict__ qb,
                                                   u16* __restrict__ kb,
                                                   u16* __restrict__ vb) {
  __shared__ __align__(16) u16 As[2][BM * BK];   // 2 x 16 KiB
  __shared__ __align__(16) u16 Bs[2][BN * BK];   // 2 x 12 KiB
  const int tid = threadIdx.x;
  const int w = tid >> 6, lane = tid & 63;
  const int fq = lane >> 4, fr = lane & 15;
  const int wr = w >> 2, wc = w & 3;             // 2M x 4N waves; per-wave C = 128x48
  const int gx = gridDim.x;
  const int swz = xcd_swz(blockIdx.y * gx + blockIdx.x, gx * gridDim.y);
  const int m0 = (swz % gx) * BM;
  const int e0 = (swz / gx) * BN;

  GEMM_KLOOP(A, Bw);

  // epilogue: BN=192 divides DM -> whole tile within one s in {q,k,v}
  const int s = e0 / DM;
  const int ecol = e0 % DM;
  const int b = m0 >> 11;
  const int l0 = m0 & (SL - 1);
  u16* outb = (s == 0) ? qb : (s == 1) ? kb : vb;
#pragma unroll
  for (int m = 0; m < 8; ++m)
#pragma unroll
    for (int n = 0; n < 3; ++n)
#pragma unroll
      for (int j = 0; j < 4; ++j) {
        int rr = wr * 128 + m * 16 + fq * 4 + j;
        int cc = ecol + wc * 48 + n * 16 + fr;
        int h = cc >> 7, d = cc & 127;
        outb[((size_t)(b * NH + h) * SL + l0 + rr) * HD + d] = f2b(acc[m][n][j]);
      }
}

// ---------------- proj GEMM: Y(fp32) = A * B^T ----------------
__global__ __launch_bounds__(512, 2) void gemm_proj(const u16* __restrict__ A,
                                                    const u16* __restrict__ Bw,
                                                    float* __restrict__ Y) {
  __shared__ __align__(16) u16 As[2][BM * BK];
  __shared__ __align__(16) u16 Bs[2][BN * BK];
  const int tid = threadIdx.x;
  const int w = tid >> 6, lane = tid & 63;
  const int fq = lane >> 4, fr = lane & 15;
  const int wr = w >> 2, wc = w & 3;
  const int gx = gridDim.x;
  const int swz = xcd_swz(blockIdx.y * gx + blockIdx.x, gx * gridDim.y);
  const int m0 = (swz % gx) * BM;
  const int e0 = (swz / gx) * BN;

  GEMM_KLOOP(A, Bw);

#pragma unroll
  for (int m = 0; m < 8; ++m)
#pragma unroll
    for (int n = 0; n < 3; ++n)
#pragma unroll
      for (int j = 0; j < 4; ++j) {
        int rr = wr * 128 + m * 16 + fq * 4 + j;
        int cc = wc * 48 + n * 16 + fr;
        Y[(size_t)(m0 + rr) * DM + e0 + cc] = acc[m][n][j];
      }
}

// ---------------- RMSNorm over Hd=128, in place, one wave per row ----------------
__global__ __launch_bounds__(256) void rmsnorm_k(u16* __restrict__ buf, const float* __restrict__ scale,
                                                 float extra) {
  int row = blockIdx.x * 4 + (threadIdx.x >> 6);
  int lane = threadIdx.x & 63;
  u16* p = buf + (size_t)row * HD + lane * 2;
  u32 u = *reinterpret_cast<const u32*>(p);
  float a = b2f((u16)(u & 0xffffu));
  float c = b2f((u16)(u >> 16));
  float ss = a*a + c*c;
#pragma unroll
  for (int m = 32; m; m >>= 1) ss += __shfl_xor(ss, m, 64);
  float rr = rsqrtf(ss * (1.0f/128.0f) + 1e-6f);
  float s0 = scale[lane*2] * extra;
  float s1 = scale[lane*2 + 1] * extra;
  u32 o = (u32)f2b(a*rr*s0) | ((u32)f2b(c*rr*s1) << 16);
  *reinterpret_cast<u32*>(p) = o;
}

// ---------------- flash attention fwd, non-causal ----------------
// grid (L/128, B*H), 8 waves (512 thr); wave w owns q rows [q0+w*16, +16).
// KV tile = 64. V transposed in LDS with XOR key-swizzle (round-4 verified:
// conflicts 2.15e8 -> 3.9e7). q pre-scaled by q_scale*log2(e)/sqrt(128).
__global__ __launch_bounds__(512) void attn_kernel(const u16* __restrict__ qb, const u16* __restrict__ kb,
                                                   const u16* __restrict__ vb, u16* __restrict__ ob) {
  __shared__ __align__(16) u16 Ksm[64*136];    // [key][hd], padded stride 136
  __shared__ __align__(16) u16 Vsm[128*72];    // transposed [hd][key-swizzled]
  __shared__ __align__(16) u16 Psm[128*72];    // [qrow][key], stride 72
  const int tid = threadIdx.x;
  const int w = tid >> 6, lane = tid & 63;
  const int fq = lane >> 4, fr = lane & 15;
  const int bh = blockIdx.y;
  const int q0 = blockIdx.x * 128;
  const u16* qrow = qb + (size_t)bh * SL * HD;
  const u16* krow = kb + (size_t)bh * SL * HD;
  const u16* vrow = vb + (size_t)bh * SL * HD;

  bf16x8 qf[4];
#pragma unroll
  for (int kk = 0; kk < 4; ++kk)
    qf[kk] = *reinterpret_cast<const bf16x8*>(qrow + (size_t)(q0 + w*16 + fr)*HD + kk*32 + fq*8);

  f32x4 o[8] = {};
  float mrow[4], lrow[4];
#pragma unroll
  for (int j = 0; j < 4; ++j) { mrow[j] = -1e30f; lrow[j] = 0.0f; }

  for (int kt = 0; kt < SL; kt += 64) {
    __syncthreads();
    for (int c = tid; c < 1024; c += 512) {
      int key = c >> 4;
      int cc = (c & 15) * 8;
      *reinterpret_cast<bf16x8*>(Ksm + key*136 + cc) =
          *reinterpret_cast<const bf16x8*>(krow + (size_t)(kt + key)*HD + cc);
      u16x8 vv = *reinterpret_cast<const u16x8*>(vrow + (size_t)(kt + key)*HD + cc);
      int skey = key ^ ((cc >> 3) & 7) << 3;
#pragma unroll
      for (int j2 = 0; j2 < 8; ++j2)
        Vsm[(cc + j2)*72 + skey] = vv[j2];
    }
    __syncthreads();

    f32x4 s[4] = {};
#pragma unroll
    for (int kk = 0; kk < 4; ++kk)
#pragma unroll
      for (int n = 0; n < 4; ++n) {
        bf16x8 kf = *reinterpret_cast<const bf16x8*>(Ksm + (n*16 + fr)*136 + kk*32 + fq*8);
        s[n] = __builtin_amdgcn_mfma_f32_16x16x32_bf16(qf[kk], kf, s[n], 0, 0, 0);
      }

    float corr[4];
#pragma unroll
    for (int j = 0; j < 4; ++j) {
      float t = fmaxf(fmaxf(s[0][j], s[1][j]), fmaxf(s[2][j], s[3][j]));
      t = fmaxf(t, __shfl_xor(t, 1, 64));
      t = fmaxf(t, __shfl_xor(t, 2, 64));
      t = fmaxf(t, __shfl_xor(t, 4, 64));
      t = fmaxf(t, __shfl_xor(t, 8, 64));
      float mn = fmaxf(mrow[j], t);
      corr[j] = fexp2(mrow[j] - mn);
      float sum = 0.0f;
#pragma unroll
      for (int n = 0; n < 4; ++n) {
        float pv = fexp2(s[n][j] - mn);
        s[n][j] = pv;
        sum += pv;
      }
      sum += __shfl_xor(sum, 1, 64);
      sum += __shfl_xor(sum, 2, 64);
      sum += __shfl_xor(sum, 4, 64);
      sum += __shfl_xor(sum, 8, 64);
      lrow[j] = lrow[j]*corr[j] + sum;
      mrow[j] = mn;
    }
#pragma unroll
    for (int nn = 0; nn < 8; ++nn)
#pragma unroll
      for (int j = 0; j < 4; ++j)
        o[nn][j] *= corr[j];

#pragma unroll
    for (int n = 0; n < 4; ++n)
#pragma unroll
      for (int j = 0; j < 4; ++j)
        Psm[(w*16 + fq*4 + j)*72 + n*16 + fr] = f2b(s[n][j]);
    __syncthreads();

#pragma unroll
    for (int kk2 = 0; kk2 < 2; ++kk2) {
      bf16x8 pf = *reinterpret_cast<const bf16x8*>(Psm + (w*16 + fr)*72 + kk2*32 + fq*8);
#pragma unroll
      for (int nn = 0; nn < 8; ++nn) {
        int row = nn*16 + fr;
        int xr = ((row >> 3) & 7) << 3;
        bf16x8 vf = *reinterpret_cast<const bf16x8*>(Vsm + row*72 + ((kk2*32 + fq*8) ^ xr));
        o[nn] = __builtin_amdgcn_mfma_f32_16x16x32_bf16(pf, vf, o[nn], 0, 0, 0);
      }
    }
  }

  const int b = bh / NH, h = bh % NH;
  u16* op = ob + (size_t)b * SL * DM + (size_t)h * HD;
#pragma unroll
  for (int nn = 0; nn < 8; ++nn)
#pragma unroll
    for (int j = 0; j < 4; ++j) {
      int r = q0 + w*16 + fq*4 + j;
      op[(size_t)r*DM + nn*16 + fr] = f2b(o[nn][j] / lrow[j]);
    }
}

extern "C" void kernel_launch(void* const* d_in, const int* in_sizes, int n_in,
                              void* d_out, int out_size, void* d_ws, size_t ws_size,
                              hipStream_t stream) {
  const float* x       = (const float*)d_in[0];
  const float* qkv_w   = (const float*)d_in[1];
  const float* q_scale = (const float*)d_in[2];
  const float* k_scale = (const float*)d_in[3];
  const float* proj_w  = (const float*)d_in[4];
  float* y = (float*)d_out;

  u16* regA = (u16*)d_ws;
  u16* regB = regA + (size_t)MM*DM;
  u16* qbuf = regB + (size_t)NE*DM;
  u16* kbuf = qbuf + (size_t)NB*NH*SL*HD;
  u16* vbuf = kbuf + (size_t)NB*NH*SL*HD;

  const int n4x = MM*DM/4, n4w = NE*DM/4, n4p = DM*DM/4;
  cvt_kernel<<<dim3((n4x + 255)/256), 256, 0, stream>>>(x, regA, n4x);
  cvt_kernel<<<dim3((n4w + 255)/256), 256, 0, stream>>>(qkv_w, regB, n4w);

  gemm_qkv<<<dim3(MM/BM, NE/BN), 512, 0, stream>>>(regA, regB, qbuf, kbuf, vbuf);

  const float QS = 1.4426950408889634f / 11.313708498984761f;  // log2(e)/sqrt(128)
  rmsnorm_k<<<dim3(NB*NH*SL/4), 256, 0, stream>>>(qbuf, q_scale, QS);
  rmsnorm_k<<<dim3(NB*NH*SL/4), 256, 0, stream>>>(kbuf, k_scale, 1.0f);

  cvt_kernel<<<dim3((n4p + 255)/256), 256, 0, stream>>>(proj_w, regB, n4p);

  attn_kernel<<<dim3(SL/128, NB*NH), 512, 0, stream>>>(qbuf, kbuf, vbuf, regA);

  gemm_proj<<<dim3(MM/BM, DM/BN), 512, 0, stream>>>(regA, regB, y);
}